// Round 6
// baseline (178.367 us; speedup 1.0000x reference)
//
#include <hip/hip_runtime.h>

typedef __attribute__((ext_vector_type(8))) short short8;
typedef __attribute__((ext_vector_type(4))) float f32x4;
typedef __attribute__((ext_vector_type(16))) float f32x16;

#define MFMA16(a, b, c) __builtin_amdgcn_mfma_f32_16x16x32_bf16((a), (b), (c), 0, 0, 0)
#define MFMA32(a, b, c) __builtin_amdgcn_mfma_f32_32x32x16_bf16((a), (b), (c), 0, 0, 0)

#if __has_builtin(__builtin_amdgcn_exp2f)
#define EXP2(x) __builtin_amdgcn_exp2f(x)
#else
#define EXP2(x) __expf((x) * 0.6931471805599453f)
#endif

__device__ __forceinline__ unsigned short f2bf(float f) {
  unsigned int u = __float_as_uint(f);
  u += 0x7FFFu + ((u >> 16) & 1u);   // RNE; inputs finite
  return (unsigned short)(u >> 16);
}

// packed f32x2 -> bf16x2 (RNE), one VALU instr
__device__ __forceinline__ unsigned int cvtpk(float lo, float hi) {
  unsigned int r;
  asm("v_cvt_pk_bf16_f32 %0, %1, %2" : "=v"(r) : "v"(lo), "v"(hi));
  return r;
}

__device__ __forceinline__ float fmax3(float a, float b, float c) {
  return fmaxf(fmaxf(a, b), c);   // clang fuses to v_max3_f32
}

__device__ __forceinline__ void gload16(const void* g, void* l) {
  __builtin_amdgcn_global_load_lds((const __attribute__((address_space(1))) void*)g,
                                   (__attribute__((address_space(3))) void*)l, 16, 0, 0);
}

// Fragment read from a 64-col (128B-row) LDS tile staged with the chunk-XOR swizzle:
// LDS(row, cc) holds the tile's chunk cc^(row&7).
__device__ __forceinline__ short8 fragld64(const unsigned short* base, int row, int kchunk) {
  int cc = kchunk ^ (row & 7);
  return *(const short8*)(base + row * 64 + cc * 8);
}

__global__ void cvt3(const float* __restrict__ a, const float* __restrict__ b,
                     const float* __restrict__ c, unsigned short* __restrict__ out, int n4) {
  const float* src = (blockIdx.z == 0) ? a : ((blockIdx.z == 1) ? b : c);
  int i = blockIdx.x * blockDim.x + threadIdx.x;
  if (i >= n4) return;
  float4 v = ((const float4*)src)[i];
  ushort4 o;
  o.x = f2bf(v.x); o.y = f2bf(v.y); o.z = f2bf(v.z); o.w = f2bf(v.w);
  ((ushort4*)(out + (size_t)blockIdx.z * (size_t)n4 * 4))[i] = o;
}

__global__ void cvt4(const float* __restrict__ a, const float* __restrict__ b,
                     const float* __restrict__ c, const float* __restrict__ d,
                     unsigned short* __restrict__ out, int n4) {
  const float* src = (blockIdx.z == 0) ? a : ((blockIdx.z == 1) ? b
                   : ((blockIdx.z == 2) ? c : d));
  int i = blockIdx.x * blockDim.x + threadIdx.x;
  if (i >= n4) return;
  float4 v = ((const float4*)src)[i];
  ushort4 o;
  o.x = f2bf(v.x); o.y = f2bf(v.y); o.z = f2bf(v.z); o.w = f2bf(v.w);
  ((ushort4*)(out + (size_t)blockIdx.z * (size_t)n4 * 4))[i] = o;
}

// mask [b][q][k] int32 -> bitmask u64 words: mw[(b*2048+q)*32 + k/64], bit i = masked.
__global__ void maskpack(const int* __restrict__ m, unsigned long long* __restrict__ mw) {
  const int lane = threadIdx.x & 63;
  const size_t wbase = ((size_t)blockIdx.x * (blockDim.x >> 6) + (threadIdx.x >> 6)) * 4ull;
#pragma unroll
  for (int u = 0; u < 4; ++u) {
    size_t word = wbase + u;
    int x = m[word * 64 + lane];
    unsigned long long bb = __ballot(x != 0);
    if (lane == 0) mw[word] = bb;
  }
}

// C[M=4096][N=1024] = A[M][K=1024] * B[N][K]^T + bias, optional scale, bf16 or f32 out.
template<bool OUT_BF16>
__global__ __launch_bounds__(256, 3) void gemm_bt(
    const unsigned short* __restrict__ Abase, const unsigned short* __restrict__ Bbase,
    const float* __restrict__ bias0, const float* __restrict__ bias1,
    const float* __restrict__ bias2, void* __restrict__ outv, float scale0)
{
  constexpr int K = 1024, N = 1024;
  const int z = blockIdx.z;
  const unsigned short* A = Abase + (size_t)z * 4194304ull;
  const unsigned short* B = Bbase + (size_t)z * 1048576ull;
  const float* bias = (z == 0) ? bias0 : ((z == 1) ? bias1 : bias2);
  const float scale = (z == 0) ? scale0 : 1.0f;

  __shared__ unsigned short ldsA[128 * 64];
  __shared__ unsigned short ldsB[128 * 64];

  const int tid = threadIdx.x;
  const int lane = tid & 63, wid = tid >> 6;
  const int c16 = lane & 15, g = lane >> 4;
  const int m0 = blockIdx.y * 128, n0 = blockIdx.x * 128;
  const int wr = (wid >> 1) * 64, wc = (wid & 1) * 64;

  f32x4 acc[4][4] = {};

  for (int kt = 0; kt < K; kt += 64) {
    __syncthreads();
#pragma unroll
    for (int i = 0; i < 4; ++i) {
      int row = i * 32 + (tid >> 3);
      int cc = tid & 7;
      int scc = cc ^ (row & 7);
      gload16(A + (size_t)(m0 + row) * K + kt + scc * 8, ldsA + row * 64 + cc * 8);
      gload16(B + (size_t)(n0 + row) * K + kt + scc * 8, ldsB + row * 64 + cc * 8);
    }
    __syncthreads();
#pragma unroll
    for (int kc = 0; kc < 2; ++kc) {
      short8 af[4], bf[4];
#pragma unroll
      for (int mi = 0; mi < 4; ++mi) af[mi] = fragld64(ldsA, wr + mi * 16 + c16, kc * 4 + g);
#pragma unroll
      for (int ni = 0; ni < 4; ++ni) bf[ni] = fragld64(ldsB, wc + ni * 16 + c16, kc * 4 + g);
#pragma unroll
      for (int mi = 0; mi < 4; ++mi)
#pragma unroll
        for (int ni = 0; ni < 4; ++ni)
          acc[mi][ni] = MFMA16(af[mi], bf[ni], acc[mi][ni]);
    }
  }

#pragma unroll
  for (int mi = 0; mi < 4; ++mi)
#pragma unroll
    for (int ni = 0; ni < 4; ++ni) {
      int col = n0 + wc + ni * 16 + c16;
      float bb = bias[col];
#pragma unroll
      for (int r = 0; r < 4; ++r) {
        int row = m0 + wr + mi * 16 + g * 4 + r;
        float v = (acc[mi][ni][r] + bb) * scale;
        if constexpr (OUT_BF16)
          ((unsigned short*)outv)[(size_t)z * 4194304ull + (size_t)row * N + col] = f2bf(v);
        else
          ((float*)outv)[(size_t)row * N + col] = v;
      }
    }
}

// Flash attention on 32x32x16 MFMA. Block = 128 threads (2 waves); wave w owns 32 q.
// grid (sl/64, H, B) = 1024 blocks. KVBLK=64, 2-phase pipelined staging, defer-max.
// Q pre-scaled by 0.125*log2(e); softmax in exp2 domain.
// Layouts: kbuf[key][d-chunks] / vt[d][key-chunks] / pbuf[q][key-chunks], all chunk-XOR.
__global__ __launch_bounds__(128, 2) void attn(
    const unsigned short* __restrict__ qh, const unsigned short* __restrict__ kh,
    const unsigned short* __restrict__ vh, const unsigned long long* __restrict__ mw,
    unsigned short* __restrict__ zout)
{
  constexpr int SL = 2048, DM = 1024, NT = SL / 64;
  const int h = blockIdx.y, b = blockIdx.z;
  const int tid = threadIdx.x, lane = tid & 63, w = tid >> 6;
  const int ql = lane & 31;        // this lane's q (column of S^T), A/B-row/col
  const int hd = lane >> 5;        // which 8-elem k-half the lane holds
  const int qa = blockIdx.x * 64 + w * 32;

  __shared__ unsigned short kbuf[2][4096];
  __shared__ unsigned short vt[2][4096];
  __shared__ unsigned short pbuf[2][2048];

  // Q B-frags: col=q=ql, k(d) = kc*16 + hd*8 + j
  short8 qf[4];
  {
    const size_t qrow = ((size_t)b * SL + qa + ql) * DM + (size_t)h * 64 + hd * 8;
#pragma unroll
    for (int kc = 0; kc < 4; ++kc)
      qf[kc] = *(const short8*)(qh + qrow + kc * 16);
  }

  f32x16 zacc0 = {}, zacc1 = {};   // d cols 0..31 / 32..63
  float mrun = -INFINITY, lrun = 0.f;

  const size_t kvbase = (size_t)b * SL * DM + (size_t)h * 64;
  const unsigned long long* mwq = mw + ((size_t)b * SL + qa + ql) * (SL / 64);

  // staging assignments (128 threads)
  const int kr0 = tid >> 3, kcc = tid & 7;   // K: rows kr0+16i, chunk kcc
  const int vkey = tid & 63, vdc0 = tid >> 6; // V: key row vkey, d-chunks vdc0+2i

  unsigned long long mwc = mwq[0];
  short8 vr[4];

  // prologue: stage tile 0 into buffer 0
#pragma unroll
  for (int i = 0; i < 4; ++i) {
    int row = kr0 + 16 * i;
    gload16(kh + kvbase + (size_t)row * DM + (kcc ^ (row & 7)) * 8,
            kbuf[0] + row * 64 + kcc * 8);
  }
#pragma unroll
  for (int i = 0; i < 4; ++i)
    vr[i] = *(const short8*)(vh + kvbase + (size_t)vkey * DM + (vdc0 + 2 * i) * 8);
#pragma unroll
  for (int i = 0; i < 4; ++i)
#pragma unroll
    for (int e = 0; e < 8; ++e) {
      int row = (vdc0 + 2 * i) * 8 + e;
      vt[0][row * 64 + (((vkey >> 3) ^ (row & 7)) * 8) + (vkey & 7)] = (unsigned short)vr[i][e];
    }

  for (int t = 0; t < NT; ++t) {
    const int cur = t & 1, nxt = cur ^ 1;
    __syncthreads();  // buf[cur] staged (per-wave vmcnt/lgkmcnt drained before barrier)

    const bool more = (t + 1 < NT);
    unsigned long long mwn = 0;
    if (more) {  // issue next tile's loads; latency hides under compute below
      const size_t kb = kvbase + (size_t)(t + 1) * 64 * DM;
#pragma unroll
      for (int i = 0; i < 4; ++i) {
        int row = kr0 + 16 * i;
        gload16(kh + kb + (size_t)row * DM + (kcc ^ (row & 7)) * 8,
                kbuf[nxt] + row * 64 + kcc * 8);
      }
#pragma unroll
      for (int i = 0; i < 4; ++i)
        vr[i] = *(const short8*)(vh + kb + (size_t)vkey * DM + (vdc0 + 2 * i) * 8);
      mwn = mwq[t + 1];
    }

    // ---- compute tile t ----
    // mask bits -> C-init (-1e10 where masked); bit(key) at mwc[key],
    // key(st,m,c) = st*32 + m*8 + c + hd*4, reg = m*4+c
    unsigned int b0 = ((unsigned int)mwc) >> (hd * 4);
    unsigned int b1 = ((unsigned int)(mwc >> 32)) >> (hd * 4);
    f32x16 s0, s1;
#pragma unroll
    for (int m = 0; m < 4; ++m) {
      unsigned int n0 = (b0 >> (m * 8)) & 0xFu;
      unsigned int n1 = (b1 >> (m * 8)) & 0xFu;
#pragma unroll
      for (int c = 0; c < 4; ++c) {
        s0[m * 4 + c] = ((n0 >> c) & 1u) ? -1e10f : 0.0f;
        s1[m * 4 + c] = ((n1 >> c) & 1u) ? -1e10f : 0.0f;
      }
    }

    // S^T = K * Q^T + bias  (D: row=key, col=q=ql)
    __builtin_amdgcn_s_setprio(1);
#pragma unroll
    for (int kc = 0; kc < 4; ++kc) {
      short8 kf0 = fragld64(kbuf[cur], ql, kc * 2 + hd);
      short8 kf1 = fragld64(kbuf[cur], 32 + ql, kc * 2 + hd);
      s0 = MFMA32(kf0, qf[kc], s0);
      s1 = MFMA32(kf1, qf[kc], s1);
    }
    __builtin_amdgcn_s_setprio(0);

    // softmax: 32 key-values in-lane for q=ql; q duplicated on lane^32 only
    float mx;
    {
      float t0 = fmax3(s0[0], s0[1], s0[2]);
      float t1 = fmax3(s0[3], s0[4], s0[5]);
      float t2 = fmax3(s0[6], s0[7], s0[8]);
      float t3 = fmax3(s0[9], s0[10], s0[11]);
      float t4 = fmax3(s0[12], s0[13], s0[14]);
      float t5 = fmax3(s0[15], s1[0], s1[1]);
      float t6 = fmax3(s1[2], s1[3], s1[4]);
      float t7 = fmax3(s1[5], s1[6], s1[7]);
      float t8 = fmax3(s1[8], s1[9], s1[10]);
      float t9 = fmax3(s1[11], s1[12], s1[13]);
      float ta = fmaxf(s1[14], s1[15]);
      float u0 = fmax3(t0, t1, t2);
      float u1 = fmax3(t3, t4, t5);
      float u2 = fmax3(t6, t7, t8);
      float u3 = fmaxf(t9, ta);
      mx = fmaxf(fmax3(u0, u1, u2), u3);
    }
    mx = fmaxf(mx, __shfl_xor(mx, 32));

    // defer-max (T13): skip rescale while tile max stays within 8 (exp2 domain)
    const bool defer = (__all(mx <= mrun + 8.f) != 0);
    const float mnew = defer ? mrun : fmaxf(mrun, mx);

#pragma unroll
    for (int i = 0; i < 16; ++i) {
      s0[i] = EXP2(s0[i] - mnew);
      s1[i] = EXP2(s1[i] - mnew);
    }
    float rs;
    {
      float a0 = (s0[0] + s0[1]) + (s0[2] + s0[3]);
      float a1 = (s0[4] + s0[5]) + (s0[6] + s0[7]);
      float a2 = (s0[8] + s0[9]) + (s0[10] + s0[11]);
      float a3 = (s0[12] + s0[13]) + (s0[14] + s0[15]);
      float a4 = (s1[0] + s1[1]) + (s1[2] + s1[3]);
      float a5 = (s1[4] + s1[5]) + (s1[6] + s1[7]);
      float a6 = (s1[8] + s1[9]) + (s1[10] + s1[11]);
      float a7 = (s1[12] + s1[13]) + (s1[14] + s1[15]);
      rs = ((a0 + a1) + (a2 + a3)) + ((a4 + a5) + (a6 + a7));
    }
    rs += __shfl_xor(rs, 32);

    if (defer) {
      lrun += rs;
    } else {
      float alpha = EXP2(mrun - mnew);
      mrun = mnew;
      lrun = lrun * alpha + rs;
#pragma unroll
      for (int reg = 0; reg < 16; ++reg) {
        float ar = __shfl(alpha, (reg & 3) + 8 * (reg >> 2) + 4 * hd);
        zacc0[reg] *= ar;
        zacc1[reg] *= ar;
      }
    }

    // P^T -> pbuf[q][key-chunks] via cvt_pk, one b64 write per (st,m)
    {
      unsigned short* pbw = pbuf[w];
#pragma unroll
      for (int st = 0; st < 2; ++st)
#pragma unroll
        for (int m = 0; m < 4; ++m) {
          uint2 pk;
          if (st == 0) {
            pk.x = cvtpk(s0[m * 4 + 0], s0[m * 4 + 1]);
            pk.y = cvtpk(s0[m * 4 + 2], s0[m * 4 + 3]);
          } else {
            pk.x = cvtpk(s1[m * 4 + 0], s1[m * 4 + 1]);
            pk.y = cvtpk(s1[m * 4 + 2], s1[m * 4 + 3]);
          }
          int chunk = st * 4 + m;
          int a16 = ql * 64 + ((chunk ^ (ql & 7)) * 8) + hd * 4;
          *(uint2*)(pbw + a16) = pk;
        }
    }

    // z += P * V  (same-wave DS ordering makes pbuf reads safe without barrier)
    __builtin_amdgcn_s_setprio(1);
#pragma unroll
    for (int kc = 0; kc < 4; ++kc) {
      short8 pf = fragld64(pbuf[w], ql, kc * 2 + hd);
      short8 vf0 = fragld64(vt[cur], ql, kc * 2 + hd);
      short8 vf1 = fragld64(vt[cur], 32 + ql, kc * 2 + hd);
      zacc0 = MFMA32(pf, vf0, zacc0);
      zacc1 = MFMA32(pf, vf1, zacc1);
    }
    __builtin_amdgcn_s_setprio(0);

    // late V writes for tile t+1 (T14 split)
    if (more) {
#pragma unroll
      for (int i = 0; i < 4; ++i)
#pragma unroll
        for (int e = 0; e < 8; ++e) {
          int row = (vdc0 + 2 * i) * 8 + e;
          vt[nxt][row * 64 + (((vkey >> 3) ^ (row & 7)) * 8) + (vkey & 7)] = (unsigned short)vr[i][e];
        }
      mwc = mwn;
    }
  }

  // z / l -> bf16, layout [b][s][h*64+d]; D row q = (reg&3)+8*(reg>>2)+4*hd, col d = ql
  float invl = 1.f / lrun;
#pragma unroll
  for (int reg = 0; reg < 16; ++reg) {
    int qrow = (reg & 3) + 8 * (reg >> 2) + 4 * hd;
    float il = __shfl(invl, qrow);
    size_t orow = ((size_t)b * SL + qa + qrow) * DM + (size_t)h * 64;
    zout[orow + ql] = f2bf(zacc0[reg] * il);
    zout[orow + 32 + ql] = f2bf(zacc1[reg] * il);
  }
}

extern "C" void kernel_launch(void* const* d_in, const int* in_sizes, int n_in,
                              void* d_out, int out_size, void* d_ws, size_t ws_size,
                              hipStream_t stream) {
  const float* q  = (const float*)d_in[0];
  const float* k  = (const float*)d_in[1];
  const float* v  = (const float*)d_in[2];
  const int* mask = (const int*)d_in[3];
  const float* Wq = (const float*)d_in[4];
  const float* bq = (const float*)d_in[5];
  const float* Wk = (const float*)d_in[6];
  const float* bk = (const float*)d_in[7];
  const float* Wv = (const float*)d_in[8];
  const float* bv = (const float*)d_in[9];
  const float* Wo = (const float*)d_in[10];
  const float* bo = (const float*)d_in[11];

  char* ws = (char*)d_ws;
  unsigned short* xbf = (unsigned short*)ws;              // q,k,v bf16: 24 MB (dead after QKV gemm)
  unsigned long long* mwb = (unsigned long long*)ws;      // mask bit-words: 1 MB (aliases xbf)
  unsigned short* wbf = (unsigned short*)(ws + 25165824); // Wq,Wk,Wv,Wo bf16: 8 MB
  unsigned short* qkv = (unsigned short*)(ws + 33554432); // qh,kh,vh bf16: 24 MB
  unsigned short* zbf = (unsigned short*)(ws + 58720256); // z bf16: 8 MB

  cvt3<<<dim3(4096, 1, 3), 256, 0, stream>>>(q, k, v, xbf, 1048576);
  cvt4<<<dim3(1024, 1, 4), 256, 0, stream>>>(Wq, Wk, Wv, Wo, wbf, 262144);

  // fused Q/K/V projections; Q scaled by 0.125*log2(e) (softmax in exp2 domain)
  gemm_bt<true><<<dim3(8, 32, 3), 256, 0, stream>>>(xbf, wbf, bq, bk, bv, (void*)qkv,
                                                    0.125f * 1.44269504088896f);
  // xbf now dead; pack mask bits in its place
  maskpack<<<8192, 256, 0, stream>>>(mask, mwb);
  attn<<<dim3(32, 16, 2), 128, 0, stream>>>(qkv, qkv + 4194304ull, qkv + 8388608ull, mwb, zbf);
  gemm_bt<false><<<dim3(8, 32, 1), 256, 0, stream>>>(zbf, wbf + 3145728ull, bo, bo, bo, d_out, 1.0f);
}

// Round 7
// 167.874 us; speedup vs baseline: 1.0625x; 1.0625x over previous
//
#include <hip/hip_runtime.h>

typedef __attribute__((ext_vector_type(8))) short short8;
typedef __attribute__((ext_vector_type(4))) float f32x4;
typedef __attribute__((ext_vector_type(16))) float f32x16;
typedef __attribute__((ext_vector_type(4))) unsigned int u32x4;

#define MFMA16(a, b, c) __builtin_amdgcn_mfma_f32_16x16x32_bf16((a), (b), (c), 0, 0, 0)
#define MFMA32(a, b, c) __builtin_amdgcn_mfma_f32_32x32x16_bf16((a), (b), (c), 0, 0, 0)

#if __has_builtin(__builtin_amdgcn_exp2f)
#define EXP2(x) __builtin_amdgcn_exp2f(x)
#else
#define EXP2(x) __expf((x) * 0.6931471805599453f)
#endif

__device__ __forceinline__ unsigned short f2bf(float f) {
  unsigned int u = __float_as_uint(f);
  u += 0x7FFFu + ((u >> 16) & 1u);   // RNE; inputs finite
  return (unsigned short)(u >> 16);
}

// packed f32x2 -> bf16x2 (RNE), one VALU instr
__device__ __forceinline__ unsigned int cvtpk(float lo, float hi) {
  unsigned int r;
  asm("v_cvt_pk_bf16_f32 %0, %1, %2" : "=v"(r) : "v"(lo), "v"(hi));
  return r;
}

__device__ __forceinline__ float fmax3(float a, float b, float c) {
  return fmaxf(fmaxf(a, b), c);   // clang fuses to v_max3_f32
}

__device__ __forceinline__ short8 mk8(unsigned int a, unsigned int b,
                                      unsigned int c, unsigned int d) {
  u32x4 u = {a, b, c, d};
  return __builtin_bit_cast(short8, u);
}

__device__ __forceinline__ void gload16(const void* g, void* l) {
  __builtin_amdgcn_global_load_lds((const __attribute__((address_space(1))) void*)g,
                                   (__attribute__((address_space(3))) void*)l, 16, 0, 0);
}

// Fragment read from a 64-col (128B-row) LDS tile staged with the chunk-XOR swizzle:
// LDS(row, cc) holds the tile's chunk cc^(row&7).
__device__ __forceinline__ short8 fragld64(const unsigned short* base, int row, int kchunk) {
  int cc = kchunk ^ (row & 7);
  return *(const short8*)(base + row * 64 + cc * 8);
}

__global__ void cvt3(const float* __restrict__ a, const float* __restrict__ b,
                     const float* __restrict__ c, unsigned short* __restrict__ out, int n4) {
  const float* src = (blockIdx.z == 0) ? a : ((blockIdx.z == 1) ? b : c);
  int i = blockIdx.x * blockDim.x + threadIdx.x;
  if (i >= n4) return;
  float4 v = ((const float4*)src)[i];
  ushort4 o;
  o.x = f2bf(v.x); o.y = f2bf(v.y); o.z = f2bf(v.z); o.w = f2bf(v.w);
  ((ushort4*)(out + (size_t)blockIdx.z * (size_t)n4 * 4))[i] = o;
}

__global__ void cvt4(const float* __restrict__ a, const float* __restrict__ b,
                     const float* __restrict__ c, const float* __restrict__ d,
                     unsigned short* __restrict__ out, int n4) {
  const float* src = (blockIdx.z == 0) ? a : ((blockIdx.z == 1) ? b
                   : ((blockIdx.z == 2) ? c : d));
  int i = blockIdx.x * blockDim.x + threadIdx.x;
  if (i >= n4) return;
  float4 v = ((const float4*)src)[i];
  ushort4 o;
  o.x = f2bf(v.x); o.y = f2bf(v.y); o.z = f2bf(v.z); o.w = f2bf(v.w);
  ((ushort4*)(out + (size_t)blockIdx.z * (size_t)n4 * 4))[i] = o;
}

// mask [b][q][k] int32 -> bitmask u64 words: mw[(b*2048+q)*32 + k/64], bit i = masked.
__global__ void maskpack(const int* __restrict__ m, unsigned long long* __restrict__ mw) {
  const int lane = threadIdx.x & 63;
  const size_t wbase = ((size_t)blockIdx.x * (blockDim.x >> 6) + (threadIdx.x >> 6)) * 4ull;
#pragma unroll
  for (int u = 0; u < 4; ++u) {
    size_t word = wbase + u;
    int x = m[word * 64 + lane];
    unsigned long long bb = __ballot(x != 0);
    if (lane == 0) mw[word] = bb;
  }
}

// vh [b*2048+s][h*64+d] bf16 -> vtg [(b*16+h)*64+d][2048] bf16 (64x64 LDS-tiled transpose)
__global__ void vtrans(const unsigned short* __restrict__ vh, unsigned short* __restrict__ vtg) {
  __shared__ unsigned short t[64][66];
  const int sx = blockIdx.x * 64, h = blockIdx.y, b = blockIdx.z;
  const int tid = threadIdx.x;
  const int r = tid >> 2, c0 = (tid & 3) * 16;
  const unsigned short* src = vh + ((size_t)(b * 2048 + sx + r)) * 1024 + h * 64 + c0;
  short8 x0 = *(const short8*)src;
  short8 x1 = *(const short8*)(src + 8);
#pragma unroll
  for (int e = 0; e < 8; ++e) {
    t[c0 + e][r] = (unsigned short)x0[e];
    t[c0 + 8 + e][r] = (unsigned short)x1[e];
  }
  __syncthreads();
  short8 y0, y1;
#pragma unroll
  for (int e = 0; e < 8; ++e) {
    y0[e] = (short)t[r][c0 + e];
    y1[e] = (short)t[r][c0 + 8 + e];
  }
  unsigned short* dst = vtg + ((size_t)((b * 16 + h) * 64 + r)) * 2048 + sx + c0;
  *(short8*)dst = y0;
  *(short8*)(dst + 8) = y1;
}

// C[M=4096][N=1024] = A[M][K=1024] * B[N][K]^T + bias, optional scale, bf16 or f32 out.
template<bool OUT_BF16>
__global__ __launch_bounds__(256, 3) void gemm_bt(
    const unsigned short* __restrict__ Abase, const unsigned short* __restrict__ Bbase,
    const float* __restrict__ bias0, const float* __restrict__ bias1,
    const float* __restrict__ bias2, void* __restrict__ outv, float scale0)
{
  constexpr int K = 1024, N = 1024;
  const int z = blockIdx.z;
  const unsigned short* A = Abase + (size_t)z * 4194304ull;
  const unsigned short* B = Bbase + (size_t)z * 1048576ull;
  const float* bias = (z == 0) ? bias0 : ((z == 1) ? bias1 : bias2);
  const float scale = (z == 0) ? scale0 : 1.0f;

  __shared__ unsigned short ldsA[128 * 64];
  __shared__ unsigned short ldsB[128 * 64];

  const int tid = threadIdx.x;
  const int lane = tid & 63, wid = tid >> 6;
  const int c16 = lane & 15, g = lane >> 4;
  const int m0 = blockIdx.y * 128, n0 = blockIdx.x * 128;
  const int wr = (wid >> 1) * 64, wc = (wid & 1) * 64;

  f32x4 acc[4][4] = {};

  for (int kt = 0; kt < K; kt += 64) {
    __syncthreads();
#pragma unroll
    for (int i = 0; i < 4; ++i) {
      int row = i * 32 + (tid >> 3);
      int cc = tid & 7;
      int scc = cc ^ (row & 7);
      gload16(A + (size_t)(m0 + row) * K + kt + scc * 8, ldsA + row * 64 + cc * 8);
      gload16(B + (size_t)(n0 + row) * K + kt + scc * 8, ldsB + row * 64 + cc * 8);
    }
    __syncthreads();
#pragma unroll
    for (int kc = 0; kc < 2; ++kc) {
      short8 af[4], bf[4];
#pragma unroll
      for (int mi = 0; mi < 4; ++mi) af[mi] = fragld64(ldsA, wr + mi * 16 + c16, kc * 4 + g);
#pragma unroll
      for (int ni = 0; ni < 4; ++ni) bf[ni] = fragld64(ldsB, wc + ni * 16 + c16, kc * 4 + g);
#pragma unroll
      for (int mi = 0; mi < 4; ++mi)
#pragma unroll
        for (int ni = 0; ni < 4; ++ni)
          acc[mi][ni] = MFMA16(af[mi], bf[ni], acc[mi][ni]);
    }
  }

#pragma unroll
  for (int mi = 0; mi < 4; ++mi)
#pragma unroll
    for (int ni = 0; ni < 4; ++ni) {
      int col = n0 + wc + ni * 16 + c16;
      float bb = bias[col];
#pragma unroll
      for (int r = 0; r < 4; ++r) {
        int row = m0 + wr + mi * 16 + g * 4 + r;
        float v = (acc[mi][ni][r] + bb) * scale;
        if constexpr (OUT_BF16)
          ((unsigned short*)outv)[(size_t)z * 4194304ull + (size_t)row * N + col] = f2bf(v);
        else
          ((float*)outv)[(size_t)row * N + col] = v;
      }
    }
}

// Flash attention on 32x32x16 MFMA. Block = 128 threads (2 waves); wave w owns 32 q.
// grid (sl/64, H, B). KVBLK=64, double-buffered K/V via global_load_lds (V from the
// pre-transposed vtg), defer-max softmax, P kept in-register via cvt_pk + permlane32_swap.
// Q pre-scaled by 0.125*log2(e); softmax in exp2 domain.
__global__ __launch_bounds__(128, 2) void attn(
    const unsigned short* __restrict__ qh, const unsigned short* __restrict__ kh,
    const unsigned short* __restrict__ vtg, const unsigned long long* __restrict__ mw,
    unsigned short* __restrict__ zout)
{
  constexpr int SL = 2048, DM = 1024, NT = SL / 64;
  const int h = blockIdx.y, b = blockIdx.z;
  const int tid = threadIdx.x, lane = tid & 63, w = tid >> 6;
  const int ql = lane & 31;        // this lane's q (column of S^T)
  const int hd = lane >> 5;        // which 8-elem k-half the lane holds
  const int qa = blockIdx.x * 64 + w * 32;

  __shared__ unsigned short kbuf[2][4096];   // K tile [key][d-chunks], xor-swizzled
  __shared__ unsigned short vbuf[2][4096];   // V^T tile [d][key-chunks], xor-swizzled

  // Q B-frags: col=q=ql, k(d) = kc*16 + hd*8 + j
  short8 qf[4];
  {
    const size_t qrow = ((size_t)b * SL + qa + ql) * DM + (size_t)h * 64 + hd * 8;
#pragma unroll
    for (int kc = 0; kc < 4; ++kc)
      qf[kc] = *(const short8*)(qh + qrow + kc * 16);
  }

  f32x16 zacc0 = {}, zacc1 = {};   // d cols 0..31 / 32..63
  float mrun = -INFINITY, lrun = 0.f;

  const size_t kbase = (size_t)b * SL * DM + (size_t)h * 64;      // kh rows [s][DM]
  const size_t vbase = (size_t)((b * 16 + h) * 64) * (size_t)SL;  // vtg rows [d][SL]
  const unsigned long long* mwq = mw + ((size_t)b * SL + qa + ql) * (SL / 64);

  const int sr = tid >> 3, scc = tid & 7;  // staging: rows sr+16i, chunk scc

  unsigned long long mwc = mwq[0];

  // prologue: stage tile 0 into buffer 0 (K and V^T, same pattern)
#pragma unroll
  for (int i = 0; i < 4; ++i) {
    int row = sr + 16 * i;
    int sc8 = (scc ^ (row & 7)) * 8;
    gload16(kh + kbase + (size_t)row * DM + sc8, kbuf[0] + row * 64 + scc * 8);
    gload16(vtg + vbase + (size_t)row * SL + sc8, vbuf[0] + row * 64 + scc * 8);
  }

  for (int t = 0; t < NT; ++t) {
    const int cur = t & 1, nxt = cur ^ 1;
    __syncthreads();  // buf[cur] staged (vmcnt drained by all waves at barrier)

    const bool more = (t + 1 < NT);
    unsigned long long mwn = 0;
    if (more) {  // issue next tile's loads; latency hides under compute below
      const size_t ko = kbase + (size_t)(t + 1) * 64 * DM;
      const size_t vo = vbase + (size_t)(t + 1) * 64;
#pragma unroll
      for (int i = 0; i < 4; ++i) {
        int row = sr + 16 * i;
        int sc8 = (scc ^ (row & 7)) * 8;
        gload16(kh + ko + (size_t)row * DM + sc8, kbuf[nxt] + row * 64 + scc * 8);
        gload16(vtg + vo + (size_t)row * SL + sc8, vbuf[nxt] + row * 64 + scc * 8);
      }
      mwn = mwq[t + 1];
    }

    // ---- compute tile t ----
    // mask bits -> C-init (-1e10 where masked); key(st,m,c) = st*32 + m*8 + c + hd*4
    unsigned int b0 = ((unsigned int)mwc) >> (hd * 4);
    unsigned int b1 = ((unsigned int)(mwc >> 32)) >> (hd * 4);
    f32x16 s0, s1;
#pragma unroll
    for (int m = 0; m < 4; ++m) {
      unsigned int n0 = (b0 >> (m * 8)) & 0xFu;
      unsigned int n1 = (b1 >> (m * 8)) & 0xFu;
#pragma unroll
      for (int c = 0; c < 4; ++c) {
        s0[m * 4 + c] = ((n0 >> c) & 1u) ? -1e10f : 0.0f;
        s1[m * 4 + c] = ((n1 >> c) & 1u) ? -1e10f : 0.0f;
      }
    }

    // S^T = K * Q^T + bias  (D: row=key, col=q=ql)
    __builtin_amdgcn_s_setprio(1);
#pragma unroll
    for (int kc = 0; kc < 4; ++kc) {
      short8 kf0 = fragld64(kbuf[cur], ql, kc * 2 + hd);
      short8 kf1 = fragld64(kbuf[cur], 32 + ql, kc * 2 + hd);
      s0 = MFMA32(kf0, qf[kc], s0);
      s1 = MFMA32(kf1, qf[kc], s1);
    }
    __builtin_amdgcn_s_setprio(0);

    // softmax: 32 key-values in-lane for q=ql; q duplicated on lane^32 only
    float mx;
    {
      float t0 = fmax3(s0[0], s0[1], s0[2]);
      float t1 = fmax3(s0[3], s0[4], s0[5]);
      float t2 = fmax3(s0[6], s0[7], s0[8]);
      float t3 = fmax3(s0[9], s0[10], s0[11]);
      float t4 = fmax3(s0[12], s0[13], s0[14]);
      float t5 = fmax3(s0[15], s1[0], s1[1]);
      float t6 = fmax3(s1[2], s1[3], s1[4]);
      float t7 = fmax3(s1[5], s1[6], s1[7]);
      float t8 = fmax3(s1[8], s1[9], s1[10]);
      float t9 = fmax3(s1[11], s1[12], s1[13]);
      float ta = fmaxf(s1[14], s1[15]);
      float u0 = fmax3(t0, t1, t2);
      float u1 = fmax3(t3, t4, t5);
      float u2 = fmax3(t6, t7, t8);
      float u3 = fmaxf(t9, ta);
      mx = fmaxf(fmax3(u0, u1, u2), u3);
    }
    mx = fmaxf(mx, __shfl_xor(mx, 32));

    // defer-max (T13): skip rescale while tile max stays within 8 (exp2 domain)
    const bool defer = (__all(mx <= mrun + 8.f) != 0);
    const float mnew = defer ? mrun : fmaxf(mrun, mx);

#pragma unroll
    for (int i = 0; i < 16; ++i) {
      s0[i] = EXP2(s0[i] - mnew);
      s1[i] = EXP2(s1[i] - mnew);
    }
    float rs;
    {
      float a0 = (s0[0] + s0[1]) + (s0[2] + s0[3]);
      float a1 = (s0[4] + s0[5]) + (s0[6] + s0[7]);
      float a2 = (s0[8] + s0[9]) + (s0[10] + s0[11]);
      float a3 = (s0[12] + s0[13]) + (s0[14] + s0[15]);
      float a4 = (s1[0] + s1[1]) + (s1[2] + s1[3]);
      float a5 = (s1[4] + s1[5]) + (s1[6] + s1[7]);
      float a6 = (s1[8] + s1[9]) + (s1[10] + s1[11]);
      float a7 = (s1[12] + s1[13]) + (s1[14] + s1[15]);
      rs = ((a0 + a1) + (a2 + a3)) + ((a4 + a5) + (a6 + a7));
    }
    rs += __shfl_xor(rs, 32);

    if (defer) {
      lrun += rs;
    } else {
      float alpha = EXP2(mrun - mnew);
      mrun = mnew;
      lrun = lrun * alpha + rs;
#pragma unroll
      for (int reg = 0; reg < 16; ++reg) {
        float ar = __shfl(alpha, (reg & 3) + 8 * (reg >> 2) + 4 * hd);
        zacc0[reg] *= ar;
        zacc1[reg] *= ar;
      }
    }

    // P -> bf16 A-frags fully in-register: cvt_pk pairs, then permlane32_swap.
    // w[i] = keys {K(hd,2i), K(hd,2i+1)}; swap(w[4m],w[4m+2]) & swap(w[4m+1],w[4m+3])
    // leave words [4m..4m+3] = A-frag for keys 16m..16m+15 (derived from swap semantics:
    // A'hi <- B lo (partner), B' lo <- A hi (partner)).
    unsigned int wv[16];
#pragma unroll
    for (int i = 0; i < 8; ++i) wv[i] = cvtpk(s0[2 * i], s0[2 * i + 1]);
#pragma unroll
    for (int i = 0; i < 8; ++i) wv[8 + i] = cvtpk(s1[2 * i], s1[2 * i + 1]);
#pragma unroll
    for (int m = 0; m < 4; ++m) {
      asm("v_permlane32_swap_b32 %0, %1" : "+v"(wv[4 * m]), "+v"(wv[4 * m + 2]));
      asm("v_permlane32_swap_b32 %0, %1" : "+v"(wv[4 * m + 1]), "+v"(wv[4 * m + 3]));
    }

    // z += P * V  (B-frags straight from the staged V^T tile)
    __builtin_amdgcn_s_setprio(1);
#pragma unroll
    for (int m = 0; m < 4; ++m) {
      short8 pf = mk8(wv[4 * m], wv[4 * m + 1], wv[4 * m + 2], wv[4 * m + 3]);
      short8 vf0 = fragld64(vbuf[cur], ql, m * 2 + hd);
      short8 vf1 = fragld64(vbuf[cur], 32 + ql, m * 2 + hd);
      zacc0 = MFMA32(pf, vf0, zacc0);
      zacc1 = MFMA32(pf, vf1, zacc1);
    }
    __builtin_amdgcn_s_setprio(0);

    mwc = mwn;
  }

  // z / l -> bf16, layout [b][s][h*64+d]; D row q = (reg&3)+8*(reg>>2)+4*hd, col d = ql
  float invl = 1.f / lrun;
#pragma unroll
  for (int reg = 0; reg < 16; ++reg) {
    int qrow = (reg & 3) + 8 * (reg >> 2) + 4 * hd;
    float il = __shfl(invl, qrow);
    size_t orow = ((size_t)b * SL + qa + qrow) * DM + (size_t)h * 64;
    zout[orow + ql] = f2bf(zacc0[reg] * il);
    zout[orow + 32 + ql] = f2bf(zacc1[reg] * il);
  }
}

extern "C" void kernel_launch(void* const* d_in, const int* in_sizes, int n_in,
                              void* d_out, int out_size, void* d_ws, size_t ws_size,
                              hipStream_t stream) {
  const float* q  = (const float*)d_in[0];
  const float* k  = (const float*)d_in[1];
  const float* v  = (const float*)d_in[2];
  const int* mask = (const int*)d_in[3];
  const float* Wq = (const float*)d_in[4];
  const float* bq = (const float*)d_in[5];
  const float* Wk = (const float*)d_in[6];
  const float* bk = (const float*)d_in[7];
  const float* Wv = (const float*)d_in[8];
  const float* bv = (const float*)d_in[9];
  const float* Wo = (const float*)d_in[10];
  const float* bo = (const float*)d_in[11];

  char* ws = (char*)d_ws;
  unsigned short* xbf = (unsigned short*)ws;              // q,k,v bf16: 24 MB (dead after QKV gemm)
  unsigned long long* mwb = (unsigned long long*)ws;      // mask bit-words: 1 MB (aliases xbf)
  unsigned short* vtg = (unsigned short*)(ws + 2097152);  // V^T bf16: 8 MB (aliases xbf)
  unsigned short* wbf = (unsigned short*)(ws + 25165824); // Wq,Wk,Wv,Wo bf16: 8 MB
  unsigned short* qkv = (unsigned short*)(ws + 33554432); // qh,kh,vh bf16: 24 MB
  unsigned short* zbf = (unsigned short*)(ws + 58720256); // z bf16: 8 MB

  cvt3<<<dim3(4096, 1, 3), 256, 0, stream>>>(q, k, v, xbf, 1048576);
  cvt4<<<dim3(1024, 1, 4), 256, 0, stream>>>(Wq, Wk, Wv, Wo, wbf, 262144);

  // fused Q/K/V projections; Q scaled by 0.125*log2(e) (softmax in exp2 domain)
  gemm_bt<true><<<dim3(8, 32, 3), 256, 0, stream>>>(xbf, wbf, bq, bk, bv, (void*)qkv,
                                                    0.125f * 1.44269504088896f);
  // xbf now dead; pack mask bits + transpose V into its place
  maskpack<<<8192, 256, 0, stream>>>(mask, mwb);
  vtrans<<<dim3(32, 16, 2), 256, 0, stream>>>(qkv + 8388608ull, vtg);
  attn<<<dim3(32, 16, 2), 128, 0, stream>>>(qkv, qkv + 4194304ull, vtg, mwb, zbf);
  gemm_bt<false><<<dim3(8, 32, 1), 256, 0, stream>>>(zbf, wbf + 3145728ull, bo, bo, bo, d_out, 1.0f);
}